// Round 2
// baseline (263.105 us; speedup 1.0000x reference)
//
#include <hip/hip_runtime.h>
#include <stdint.h>

typedef unsigned short u16;
typedef __bf16 bfrag __attribute__((ext_vector_type(8)));   // 8 x bf16 = 4 VGPRs (MFMA A/B frag)
typedef float f32x4 __attribute__((ext_vector_type(4)));    // MFMA C/D frag

__device__ __forceinline__ float bf2f(u16 u) {
  union { unsigned i; float f; } x; x.i = ((unsigned)u) << 16; return x.f;
}
__device__ __forceinline__ u16 f2bf(float f) {
  union { unsigned i; float f; } x; x.f = f;
  unsigned r = x.i + 0x7fffu + ((x.i >> 16) & 1u);   // RNE
  return (u16)(r >> 16);
}

__device__ __forceinline__ f32x4 mfma16(bfrag a, bfrag b, f32x4 c) {
  return __builtin_amdgcn_mfma_f32_16x16x32_bf16(a, b, c, 0, 0, 0);
}

// ---------------- weight transpose: in (R x C) f32 -> out (C x R) bf16 ----------------
__global__ __launch_bounds__(256) void k_transpose(const float* __restrict__ in,
                                                   u16* __restrict__ out, int R, int C) {
  __shared__ u16 tile[32][33];
  int c0 = blockIdx.x * 32, r0 = blockIdx.y * 32;
  int tx = threadIdx.x, ty = threadIdx.y;   // (32,8)
#pragma unroll
  for (int i = 0; i < 4; ++i)
    tile[ty + i * 8][tx] = f2bf(in[(size_t)(r0 + ty + i * 8) * C + c0 + tx]);
  __syncthreads();
#pragma unroll
  for (int i = 0; i < 4; ++i)
    out[(size_t)(c0 + ty + i * 8) * R + r0 + tx] = tile[tx][ty + i * 8];
}

// ---------------- cast f32 -> bf16, 8 elems/thread ----------------
__global__ __launch_bounds__(256) void k_cast(const float* __restrict__ in,
                                              u16* __restrict__ out, int n8) {
  int i = blockIdx.x * 256 + threadIdx.x;
  if (i >= n8) return;
  float4 a = *(const float4*)(in + (size_t)i * 8);
  float4 b = *(const float4*)(in + (size_t)i * 8 + 4);
  uint4 ov; u16* po = (u16*)&ov;
  po[0] = f2bf(a.x); po[1] = f2bf(a.y); po[2] = f2bf(a.z); po[3] = f2bf(a.w);
  po[4] = f2bf(b.x); po[5] = f2bf(b.y); po[6] = f2bf(b.z); po[7] = f2bf(b.w);
  *(uint4*)(out + (size_t)i * 8) = ov;
}

// ---------------- LayerNorm over last dim (2048), f32 in -> bf16 out ----------------
__global__ __launch_bounds__(256) void k_layernorm(const float* __restrict__ y,
                                                   const float* __restrict__ g,
                                                   const float* __restrict__ bb,
                                                   u16* __restrict__ yn) {
  int row = blockIdx.x, t = threadIdx.x;
  const float* yr = y + (size_t)row * 2048 + t * 8;
  float4 v0 = *(const float4*)(yr);
  float4 v1 = *(const float4*)(yr + 4);
  float x[8] = {v0.x, v0.y, v0.z, v0.w, v1.x, v1.y, v1.z, v1.w};
  float s = 0.f, ss = 0.f;
#pragma unroll
  for (int j = 0; j < 8; ++j) { s += x[j]; ss += x[j] * x[j]; }
#pragma unroll
  for (int off = 32; off > 0; off >>= 1) {
    s += __shfl_down(s, off);
    ss += __shfl_down(ss, off);
  }
  __shared__ float rs[4], rq[4];
  int lane = t & 63, wid = t >> 6;
  if (lane == 0) { rs[wid] = s; rq[wid] = ss; }
  __syncthreads();
  float S = rs[0] + rs[1] + rs[2] + rs[3];
  float Q = rq[0] + rq[1] + rq[2] + rq[3];
  float mean = S * (1.f / 2048.f);
  float var = Q * (1.f / 2048.f) - mean * mean;
  float rstd = rsqrtf(var + 1e-5f);
  float4 g0 = *(const float4*)(g + t * 8);
  float4 g1 = *(const float4*)(g + t * 8 + 4);
  float4 b0 = *(const float4*)(bb + t * 8);
  float4 b1 = *(const float4*)(bb + t * 8 + 4);
  float gg[8] = {g0.x, g0.y, g0.z, g0.w, g1.x, g1.y, g1.z, g1.w};
  float bv[8] = {b0.x, b0.y, b0.z, b0.w, b1.x, b1.y, b1.z, b1.w};
  uint4 ov; u16* po = (u16*)&ov;
#pragma unroll
  for (int j = 0; j < 8; ++j)
    po[j] = f2bf((x[j] - mean) * rstd * gg[j] + bv[j]);
  *(uint4*)(yn + (size_t)row * 2048 + t * 8) = ov;
}

// ---------------- GEMM: C(MxN) = scale * A(MxK) @ Bt(NxK)^T, bf16 in, fp32 accum ----------------
// 128x128 tile, BK=32, 256 threads = 4 waves (2x2), each wave 64x64 = 4x4 16x16x32 MFMAs.
template <bool F32OUT>
__global__ __launch_bounds__(256) void k_gemm_bt(const u16* __restrict__ A,
                                                 const u16* __restrict__ Bt,
                                                 void* __restrict__ Cv,
                                                 int M, int N, int K, float scale) {
  __shared__ __align__(16) u16 As[128 * 32];
  __shared__ __align__(16) u16 Bs[128 * 32];
  int t = threadIdx.x;
  int lane = t & 63, wid = t >> 6;
  int wm = wid >> 1, wn = wid & 1;
  int m0 = blockIdx.y * 128, n0 = blockIdx.x * 128;
  int lr = lane & 15, lg = lane >> 4;

  f32x4 acc[4][4];
#pragma unroll
  for (int i = 0; i < 4; ++i)
#pragma unroll
    for (int j = 0; j < 4; ++j) acc[i][j] = (f32x4){0.f, 0.f, 0.f, 0.f};

  for (int k0 = 0; k0 < K; k0 += 32) {
#pragma unroll
    for (int c = 0; c < 2; ++c) {
      int idx = t + c * 256;            // 0..511
      int row = idx >> 2, cg = idx & 3; // 128 rows x 4 chunks of 8 bf16
      uint4 va = *(const uint4*)(A + (size_t)(m0 + row) * K + k0 + cg * 8);
      *(uint4*)(As + row * 32 + cg * 8) = va;
      uint4 vb = *(const uint4*)(Bt + (size_t)(n0 + row) * K + k0 + cg * 8);
      *(uint4*)(Bs + row * 32 + cg * 8) = vb;
    }
    __syncthreads();
    bfrag a[4], b[4];
#pragma unroll
    for (int i = 0; i < 4; ++i)
      a[i] = *(const bfrag*)(As + (wm * 64 + i * 16 + lr) * 32 + lg * 8);
#pragma unroll
    for (int j = 0; j < 4; ++j)
      b[j] = *(const bfrag*)(Bs + (wn * 64 + j * 16 + lr) * 32 + lg * 8);
#pragma unroll
    for (int i = 0; i < 4; ++i)
#pragma unroll
      for (int j = 0; j < 4; ++j)
        acc[i][j] = mfma16(a[i], b[j], acc[i][j]);
    __syncthreads();
  }
  // epilogue: D lane holds col = lane&15, rows = (lane>>4)*4 + reg
#pragma unroll
  for (int i = 0; i < 4; ++i)
#pragma unroll
    for (int j = 0; j < 4; ++j) {
      int r0 = m0 + wm * 64 + i * 16 + lg * 4;
      int c0 = n0 + wn * 64 + j * 16 + lr;
#pragma unroll
      for (int r = 0; r < 4; ++r) {
        float v = scale * acc[i][j][r];
        if (F32OUT)
          ((float*)Cv)[(size_t)(r0 + r) * N + c0] = v;
        else
          ((u16*)Cv)[(size_t)(r0 + r) * N + c0] = f2bf(v);
      }
    }
}

// ---------------- fused attention ----------------
// grid: (16 q-chunks of 128, 64 = b*16+h). 256 threads = 4 waves, each wave 32 q-rows.
// q layout: (b,2048,1024) bf16, head h at cols h*64.. (already *scale'd).
// kv layout: (b*512, 2048) bf16: cols [0,1024) = K, [1024,2048) = V.
// out ao: (b,2048,1024) bf16 merged heads.
__global__ __launch_bounds__(256) void k_attn(const u16* __restrict__ q,
                                              const u16* __restrict__ kv,
                                              u16* __restrict__ ao) {
  __shared__ __align__(16) u16 Ks[128 * 64];    // [key][d]
  __shared__ __align__(16) u16 Vt[64 * 128];    // [d][key]
  __shared__ __align__(16) u16 Ps[4][32 * 128]; // per-wave P tile [qrow][key]
  int t = threadIdx.x, lane = t & 63, wid = t >> 6;
  int lr = lane & 15, lg = lane >> 4;
  int bh = blockIdx.y, b = bh >> 4, h = bh & 15;
  int q0 = blockIdx.x * 128 + wid * 32;

  const u16* qg = q + (size_t)(b * 2048 + q0) * 1024 + h * 64;
  bfrag qf[2][2];
#pragma unroll
  for (int rt = 0; rt < 2; ++rt)
#pragma unroll
    for (int kk = 0; kk < 2; ++kk)
      qf[rt][kk] = *(const bfrag*)(qg + (size_t)(rt * 16 + lr) * 1024 + kk * 32 + lg * 8);

  f32x4 o[2][4];
  f32x4 m_[2], l_[2];
#pragma unroll
  for (int rt = 0; rt < 2; ++rt) {
    m_[rt] = (f32x4){-1e30f, -1e30f, -1e30f, -1e30f};
    l_[rt] = (f32x4){0.f, 0.f, 0.f, 0.f};
#pragma unroll
    for (int dt = 0; dt < 4; ++dt) o[rt][dt] = (f32x4){0.f, 0.f, 0.f, 0.f};
  }

  const u16* kg = kv + (size_t)(b * 512) * 2048 + h * 64;
  const u16* vg = kg + 1024;

  for (int it = 0; it < 4; ++it) {
    int kv0 = it * 128;
#pragma unroll
    for (int c = 0; c < 4; ++c) {
      int idx = t + c * 256;             // 0..1023
      int row = idx >> 3, d0 = (idx & 7) * 8;
      *(uint4*)(Ks + row * 64 + d0) = *(const uint4*)(kg + (size_t)(kv0 + row) * 2048 + d0);
      uint4 vv = *(const uint4*)(vg + (size_t)(kv0 + row) * 2048 + d0);
      const u16* pv = (const u16*)&vv;
#pragma unroll
      for (int e = 0; e < 8; ++e) Vt[(d0 + e) * 128 + row] = pv[e];
    }
    __syncthreads();

    // S = Q @ K^T  (per wave: 32 x 128)
    f32x4 s[2][8];
#pragma unroll
    for (int rt = 0; rt < 2; ++rt)
#pragma unroll
      for (int ct = 0; ct < 8; ++ct) {
        s[rt][ct] = (f32x4){0.f, 0.f, 0.f, 0.f};
#pragma unroll
        for (int kk = 0; kk < 2; ++kk) {
          bfrag kf = *(const bfrag*)(Ks + (ct * 16 + lr) * 64 + kk * 32 + lg * 8);
          s[rt][ct] = mfma16(qf[rt][kk], kf, s[rt][ct]);
        }
      }

    // online softmax per row-tile (rows live across 16-lane groups: row = lg*4+r)
#pragma unroll
    for (int rt = 0; rt < 2; ++rt) {
      f32x4 mn = m_[rt];
#pragma unroll
      for (int ct = 0; ct < 8; ++ct)
#pragma unroll
        for (int r = 0; r < 4; ++r) mn[r] = fmaxf(mn[r], s[rt][ct][r]);
#pragma unroll
      for (int off = 1; off < 16; off <<= 1)
#pragma unroll
        for (int r = 0; r < 4; ++r) mn[r] = fmaxf(mn[r], __shfl_xor(mn[r], off));
      f32x4 sc, ps;
#pragma unroll
      for (int r = 0; r < 4; ++r) { sc[r] = __expf(m_[rt][r] - mn[r]); ps[r] = 0.f; }
#pragma unroll
      for (int ct = 0; ct < 8; ++ct)
#pragma unroll
        for (int r = 0; r < 4; ++r) {
          float p = __expf(s[rt][ct][r] - mn[r]);
          s[rt][ct][r] = p;
          ps[r] += p;
        }
#pragma unroll
      for (int off = 1; off < 16; off <<= 1)
#pragma unroll
        for (int r = 0; r < 4; ++r) ps[r] += __shfl_xor(ps[r], off);
#pragma unroll
      for (int r = 0; r < 4; ++r) {
        l_[rt][r] = l_[rt][r] * sc[r] + ps[r];
        m_[rt][r] = mn[r];
      }
#pragma unroll
      for (int dt = 0; dt < 4; ++dt)
#pragma unroll
        for (int r = 0; r < 4; ++r) o[rt][dt][r] *= sc[r];
#pragma unroll
      for (int ct = 0; ct < 8; ++ct)
#pragma unroll
        for (int r = 0; r < 4; ++r)
          Ps[wid][(rt * 16 + lg * 4 + r) * 128 + ct * 16 + lr] = f2bf(s[rt][ct][r]);
    }
    asm volatile("s_waitcnt lgkmcnt(0)" ::: "memory");  // own-wave P writes visible (DS in-order)

    // O += P @ V
#pragma unroll
    for (int rt = 0; rt < 2; ++rt)
#pragma unroll
      for (int dt = 0; dt < 4; ++dt)
#pragma unroll
        for (int kt = 0; kt < 4; ++kt) {
          bfrag pf = *(const bfrag*)(&Ps[wid][(rt * 16 + lr) * 128 + kt * 32 + lg * 8]);
          bfrag vfb = *(const bfrag*)(Vt + (dt * 16 + lr) * 128 + kt * 32 + lg * 8);
          o[rt][dt] = mfma16(pf, vfb, o[rt][dt]);
        }
    __syncthreads();
  }

  // epilogue: normalize and store merged heads
#pragma unroll
  for (int rt = 0; rt < 2; ++rt) {
    f32x4 inv;
#pragma unroll
    for (int r = 0; r < 4; ++r) inv[r] = 1.f / l_[rt][r];
#pragma unroll
    for (int dt = 0; dt < 4; ++dt)
#pragma unroll
      for (int r = 0; r < 4; ++r)
        ao[(size_t)(b * 2048 + q0 + rt * 16 + lg * 4 + r) * 1024 + h * 64 + dt * 16 + lr] =
            f2bf(o[rt][dt][r] * inv[r]);
  }
}

extern "C" void kernel_launch(void* const* d_in, const int* in_sizes, int n_in,
                              void* d_out, int out_size, void* d_ws, size_t ws_size,
                              hipStream_t stream) {
  const float* y   = (const float*)d_in[0];
  const float* vf  = (const float*)d_in[1];
  const float* g   = (const float*)d_in[2];
  const float* bb  = (const float*)d_in[3];
  const float* Wq  = (const float*)d_in[4];
  const float* Wkv = (const float*)d_in[5];
  const float* Wo  = (const float*)d_in[6];
  float* out = (float*)d_out;
  char* ws = (char*)d_ws;

  // Workspace layout (bf16 buffers), 56 MB total:
  u16* qb   = (u16*)(ws + 0ull);          // 8192x1024  (16 MB)
  u16* kvb  = (u16*)(ws + 16777216ull);   // 2048x2048  ( 8 MB)
  u16* aob  = (u16*)(ws + 25165824ull);   // 8192x1024  (16 MB)
  u16* wqT  = (u16*)(ws + 41943040ull);   // 1024x2048  ( 4 MB)
  u16* wkvT = (u16*)(ws + 46137344ull);   // 2048x1024  ( 4 MB)
  u16* woT  = (u16*)(ws + 50331648ull);   // 2048x1024  ( 4 MB)
  u16* vfb  = (u16*)(ws + 54525952ull);   // 2048x1024  ( 4 MB)
  // yn (8192x2048 bf16 = 32 MB) lives in d_out (64 MB f32) — consumed by the
  // Q-GEMM, then d_out is fully overwritten by the final GEMM. Deterministic.
  u16* yn = (u16*)d_out;

  dim3 tb(32, 8, 1);
  k_transpose<<<dim3(1024 / 32, 2048 / 32, 1), tb, 0, stream>>>(Wq, wqT, 2048, 1024);
  k_transpose<<<dim3(2048 / 32, 1024 / 32, 1), tb, 0, stream>>>(Wkv, wkvT, 1024, 2048);
  k_transpose<<<dim3(2048 / 32, 1024 / 32, 1), tb, 0, stream>>>(Wo, woT, 1024, 2048);
  k_cast<<<(2048 * 1024 / 8 + 255) / 256, 256, 0, stream>>>(vf, vfb, 2048 * 1024 / 8);
  k_layernorm<<<8192, 256, 0, stream>>>(y, g, bb, yn);
  // q = LN(y) @ Wq * 1/sqrt(64)
  k_gemm_bt<false><<<dim3(1024 / 128, 8192 / 128, 1), 256, 0, stream>>>(yn, wqT, qb, 8192, 1024, 2048, 0.125f);
  // kv = vis @ Wkv
  k_gemm_bt<false><<<dim3(2048 / 128, 2048 / 128, 1), 256, 0, stream>>>(vfb, wkvT, kvb, 2048, 2048, 1024, 1.0f);
  k_attn<<<dim3(16, 64, 1), 256, 0, stream>>>(qb, kvb, aob);
  // out = ao @ Wo (f32 out)
  k_gemm_bt<true><<<dim3(2048 / 128, 8192 / 128, 1), 256, 0, stream>>>(aob, woT, out, 8192, 2048, 1024, 1.0f);
}

// Round 3
// 218.423 us; speedup vs baseline: 1.2046x; 1.2046x over previous
//
#include <hip/hip_runtime.h>
#include <stdint.h>

typedef unsigned short u16;
typedef __bf16 bfrag __attribute__((ext_vector_type(8)));   // 8 x bf16 = 4 VGPRs (MFMA A/B frag)
typedef float f32x4 __attribute__((ext_vector_type(4)));    // MFMA C/D frag

__device__ __forceinline__ float bf2f(u16 u) {
  union { unsigned i; float f; } x; x.i = ((unsigned)u) << 16; return x.f;
}
__device__ __forceinline__ u16 f2bf(float f) {
  union { unsigned i; float f; } x; x.f = f;
  unsigned r = x.i + 0x7fffu + ((x.i >> 16) & 1u);   // RNE
  return (u16)(r >> 16);
}

__device__ __forceinline__ f32x4 mfma16(bfrag a, bfrag b, f32x4 c) {
  return __builtin_amdgcn_mfma_f32_16x16x32_bf16(a, b, c, 0, 0, 0);
}

// async global->LDS, 16B per lane. LDS dest = wave-uniform base + lane*16.
__device__ __forceinline__ void gl_lds16(const u16* g, const u16* l) {
  __builtin_amdgcn_global_load_lds(
      (const __attribute__((address_space(1))) unsigned int*)g,
      (__attribute__((address_space(3))) unsigned int*)l, 16, 0, 0);
}

// ---------------- weight transpose: in (R x C) f32 -> out (C x R) bf16 ----------------
__global__ __launch_bounds__(256) void k_transpose(const float* __restrict__ in,
                                                   u16* __restrict__ out, int R, int C) {
  __shared__ u16 tile[32][33];
  int c0 = blockIdx.x * 32, r0 = blockIdx.y * 32;
  int tx = threadIdx.x, ty = threadIdx.y;   // (32,8)
#pragma unroll
  for (int i = 0; i < 4; ++i)
    tile[ty + i * 8][tx] = f2bf(in[(size_t)(r0 + ty + i * 8) * C + c0 + tx]);
  __syncthreads();
#pragma unroll
  for (int i = 0; i < 4; ++i)
    out[(size_t)(c0 + ty + i * 8) * R + r0 + tx] = tile[tx][ty + i * 8];
}

// ---------------- cast f32 -> bf16, 8 elems/thread ----------------
__global__ __launch_bounds__(256) void k_cast(const float* __restrict__ in,
                                              u16* __restrict__ out, int n8) {
  int i = blockIdx.x * 256 + threadIdx.x;
  if (i >= n8) return;
  float4 a = *(const float4*)(in + (size_t)i * 8);
  float4 b = *(const float4*)(in + (size_t)i * 8 + 4);
  uint4 ov; u16* po = (u16*)&ov;
  po[0] = f2bf(a.x); po[1] = f2bf(a.y); po[2] = f2bf(a.z); po[3] = f2bf(a.w);
  po[4] = f2bf(b.x); po[5] = f2bf(b.y); po[6] = f2bf(b.z); po[7] = f2bf(b.w);
  *(uint4*)(out + (size_t)i * 8) = ov;
}

// ---------------- LayerNorm over last dim (2048), f32 in -> bf16 out ----------------
__global__ __launch_bounds__(256) void k_layernorm(const float* __restrict__ y,
                                                   const float* __restrict__ g,
                                                   const float* __restrict__ bb,
                                                   u16* __restrict__ yn) {
  int row = blockIdx.x, t = threadIdx.x;
  const float* yr = y + (size_t)row * 2048 + t * 8;
  float4 v0 = *(const float4*)(yr);
  float4 v1 = *(const float4*)(yr + 4);
  float x[8] = {v0.x, v0.y, v0.z, v0.w, v1.x, v1.y, v1.z, v1.w};
  float s = 0.f, ss = 0.f;
#pragma unroll
  for (int j = 0; j < 8; ++j) { s += x[j]; ss += x[j] * x[j]; }
#pragma unroll
  for (int off = 32; off > 0; off >>= 1) {
    s += __shfl_down(s, off);
    ss += __shfl_down(ss, off);
  }
  __shared__ float rs[4], rq[4];
  int lane = t & 63, wid = t >> 6;
  if (lane == 0) { rs[wid] = s; rq[wid] = ss; }
  __syncthreads();
  float S = rs[0] + rs[1] + rs[2] + rs[3];
  float Q = rq[0] + rq[1] + rq[2] + rq[3];
  float mean = S * (1.f / 2048.f);
  float var = Q * (1.f / 2048.f) - mean * mean;
  float rstd = rsqrtf(var + 1e-5f);
  float4 g0 = *(const float4*)(g + t * 8);
  float4 g1 = *(const float4*)(g + t * 8 + 4);
  float4 b0 = *(const float4*)(bb + t * 8);
  float4 b1 = *(const float4*)(bb + t * 8 + 4);
  float gg[8] = {g0.x, g0.y, g0.z, g0.w, g1.x, g1.y, g1.z, g1.w};
  float bv[8] = {b0.x, b0.y, b0.z, b0.w, b1.x, b1.y, b1.z, b1.w};
  uint4 ov; u16* po = (u16*)&ov;
#pragma unroll
  for (int j = 0; j < 8; ++j)
    po[j] = f2bf((x[j] - mean) * rstd * gg[j] + bv[j]);
  *(uint4*)(yn + (size_t)row * 2048 + t * 8) = ov;
}

// ---------------- GEMM: C(MxN) = scale * A(MxK) @ Bt(NxK)^T, bf16 in, fp32 accum ----------------
// 128x128 tile, BK=64, 4 waves (2x2), each wave 64x64 = 4x4 16x16x32 MFMAs x 2 k-halves.
// Staging: global_load_lds w=16, pre-swizzled source; LDS rows 128B, chunk swizzle c^(row&7).
template <bool F32OUT>
__global__ __launch_bounds__(256) void k_gemm_bt(const u16* __restrict__ A,
                                                 const u16* __restrict__ Bt,
                                                 void* __restrict__ Cv,
                                                 int M, int N, int K, float scale) {
  __shared__ __align__(16) u16 As[128 * 64];
  __shared__ __align__(16) u16 Bs[128 * 64];
  int t = threadIdx.x, lane = t & 63, wid = t >> 6;
  int wm = wid >> 1, wn = wid & 1;
  int m0 = blockIdx.y * 128, n0 = blockIdx.x * 128;
  int lr = lane & 15, lg = lane >> 4;
  int sk = lr & 7;   // read-side swizzle key (= row&7 for all fragment rows)

  f32x4 acc[4][4];
#pragma unroll
  for (int i = 0; i < 4; ++i)
#pragma unroll
    for (int j = 0; j < 4; ++j) acc[i][j] = (f32x4){0.f, 0.f, 0.f, 0.f};

  // per-lane staging geometry (constant across K-steps)
  int srow[4], scol[4], sbase[4];
#pragma unroll
  for (int j = 0; j < 4; ++j) {
    int s0 = (wid * 4 + j) * 64;
    int s = s0 + lane;
    srow[j] = s >> 3;
    scol[j] = ((s & 7) ^ (srow[j] & 7)) * 8;
    sbase[j] = s0 * 8;   // u16 offset of wave-uniform LDS base
  }

  for (int k0 = 0; k0 < K; k0 += 64) {
#pragma unroll
    for (int j = 0; j < 4; ++j) {
      gl_lds16(A + (size_t)(m0 + srow[j]) * K + k0 + scol[j], As + sbase[j]);
      gl_lds16(Bt + (size_t)(n0 + srow[j]) * K + k0 + scol[j], Bs + sbase[j]);
    }
    __syncthreads();
#pragma unroll
    for (int kk = 0; kk < 2; ++kk) {
      bfrag a[4], b[4];
#pragma unroll
      for (int i = 0; i < 4; ++i)
        a[i] = *(const bfrag*)(As + (wm * 64 + i * 16 + lr) * 64 + (((kk * 4 + lg) ^ sk) * 8));
#pragma unroll
      for (int j = 0; j < 4; ++j)
        b[j] = *(const bfrag*)(Bs + (wn * 64 + j * 16 + lr) * 64 + (((kk * 4 + lg) ^ sk) * 8));
#pragma unroll
      for (int i = 0; i < 4; ++i)
#pragma unroll
        for (int j = 0; j < 4; ++j)
          acc[i][j] = mfma16(a[i], b[j], acc[i][j]);
    }
    __syncthreads();
  }
  // epilogue: D lane holds col = lane&15, rows = (lane>>4)*4 + reg
#pragma unroll
  for (int i = 0; i < 4; ++i)
#pragma unroll
    for (int j = 0; j < 4; ++j) {
      int r0 = m0 + wm * 64 + i * 16 + lg * 4;
      int c0 = n0 + wn * 64 + j * 16 + lr;
#pragma unroll
      for (int r = 0; r < 4; ++r) {
        float v = scale * acc[i][j][r];
        if (F32OUT)
          ((float*)Cv)[(size_t)(r0 + r) * N + c0] = v;
        else
          ((u16*)Cv)[(size_t)(r0 + r) * N + c0] = f2bf(v);
      }
    }
}

// ---------------- fused attention ----------------
// grid: (16 q-chunks of 128, 64 = b*16+h). 4 waves, each wave 32 q-rows. KVBLK=128.
// All LDS tiles XOR-swizzled; K staged via global_load_lds with pre-swizzled source.
__global__ __launch_bounds__(256) void k_attn(const u16* __restrict__ q,
                                              const u16* __restrict__ kv,
                                              u16* __restrict__ ao) {
  __shared__ __align__(16) u16 Ks[128 * 64];    // [key][d], 128B rows, swz key row&7
  __shared__ __align__(16) u16 Vt[64 * 128];    // [d][key], 256B rows, swz key (d&7)^(d>>3)
  __shared__ __align__(16) u16 Ps[4][16 * 128]; // per-wave P tile [qrow(16)][key], swz row&7
  int t = threadIdx.x, lane = t & 63, wid = t >> 6;
  int lr = lane & 15, lg = lane >> 4;
  int sk = lr & 7;
  int bh = blockIdx.y, b = bh >> 4, h = bh & 15;
  int q0 = blockIdx.x * 128 + wid * 32;

  const u16* qg = q + (size_t)(b * 2048 + q0) * 1024 + h * 64;
  bfrag qf[2][2];
#pragma unroll
  for (int rt = 0; rt < 2; ++rt)
#pragma unroll
    for (int kk = 0; kk < 2; ++kk)
      qf[rt][kk] = *(const bfrag*)(qg + (size_t)(rt * 16 + lr) * 1024 + kk * 32 + lg * 8);

  f32x4 o[2][4];
  f32x4 m_[2], l_[2];
#pragma unroll
  for (int rt = 0; rt < 2; ++rt) {
    m_[rt] = (f32x4){-1e30f, -1e30f, -1e30f, -1e30f};
    l_[rt] = (f32x4){0.f, 0.f, 0.f, 0.f};
#pragma unroll
    for (int dt = 0; dt < 4; ++dt) o[rt][dt] = (f32x4){0.f, 0.f, 0.f, 0.f};
  }

  const u16* kg = kv + (size_t)(b * 512) * 2048 + h * 64;
  const u16* vg = kg + 1024;

  // K staging geometry
  int krow[4], kcol[4], kbase[4];
#pragma unroll
  for (int j = 0; j < 4; ++j) {
    int s0 = (wid * 4 + j) * 64;
    int s = s0 + lane;
    krow[j] = s >> 3;
    kcol[j] = ((s & 7) ^ (krow[j] & 7)) * 8;
    kbase[j] = s0 * 8;
  }

  for (int it = 0; it < 4; ++it) {
    int kv0 = it * 128;
    // K: async direct-to-LDS, pre-swizzled source
#pragma unroll
    for (int j = 0; j < 4; ++j)
      gl_lds16(kg + (size_t)(kv0 + krow[j]) * 2048 + kcol[j], Ks + kbase[j]);
    // V: reg-staged transpose with swizzled scalar writes (conflict-free both sides)
#pragma unroll
    for (int c = 0; c < 4; ++c) {
      int idx = t + c * 256;             // 0..1023
      int row = idx >> 3, d0 = (idx & 7) * 8;
      uint4 vv = *(const uint4*)(vg + (size_t)(kv0 + row) * 2048 + d0);
      const u16* pv = (const u16*)&vv;
#pragma unroll
      for (int e = 0; e < 8; ++e) {
        int d = d0 + e;
        int fv = (d & 7) ^ ((d >> 3) & 7);
        Vt[d * 128 + (row ^ (fv << 3))] = pv[e];
      }
    }
    __syncthreads();

#pragma unroll
    for (int rt = 0; rt < 2; ++rt) {
      // S = Q @ K^T (this row-tile: 16 x 128)
      f32x4 s[8];
#pragma unroll
      for (int ct = 0; ct < 8; ++ct) {
        s[ct] = (f32x4){0.f, 0.f, 0.f, 0.f};
#pragma unroll
        for (int kk = 0; kk < 2; ++kk) {
          bfrag kf = *(const bfrag*)(Ks + (ct * 16 + lr) * 64 + (((kk * 4 + lg) ^ sk) * 8));
          s[ct] = mfma16(qf[rt][kk], kf, s[ct]);
        }
      }
      // online softmax (rows = lg*4+r)
      f32x4 mn = m_[rt];
#pragma unroll
      for (int ct = 0; ct < 8; ++ct)
#pragma unroll
        for (int r = 0; r < 4; ++r) mn[r] = fmaxf(mn[r], s[ct][r]);
#pragma unroll
      for (int off = 1; off < 16; off <<= 1)
#pragma unroll
        for (int r = 0; r < 4; ++r) mn[r] = fmaxf(mn[r], __shfl_xor(mn[r], off));
      f32x4 sc, ps;
#pragma unroll
      for (int r = 0; r < 4; ++r) { sc[r] = __expf(m_[rt][r] - mn[r]); ps[r] = 0.f; }
#pragma unroll
      for (int ct = 0; ct < 8; ++ct)
#pragma unroll
        for (int r = 0; r < 4; ++r) {
          float p = __expf(s[ct][r] - mn[r]);
          s[ct][r] = p;
          ps[r] += p;
        }
#pragma unroll
      for (int off = 1; off < 16; off <<= 1)
#pragma unroll
        for (int r = 0; r < 4; ++r) ps[r] += __shfl_xor(ps[r], off);
#pragma unroll
      for (int r = 0; r < 4; ++r) {
        l_[rt][r] = l_[rt][r] * sc[r] + ps[r];
        m_[rt][r] = mn[r];
      }
#pragma unroll
      for (int dt = 0; dt < 4; ++dt)
#pragma unroll
        for (int r = 0; r < 4; ++r) o[rt][dt][r] *= sc[r];
      // P -> wave-private LDS (swizzled)
#pragma unroll
      for (int ct = 0; ct < 8; ++ct)
#pragma unroll
        for (int r = 0; r < 4; ++r) {
          int row = lg * 4 + r;
          Ps[wid][row * 128 + ((ct * 16 + lr) ^ ((row & 7) << 3))] = f2bf(s[ct][r]);
        }
      asm volatile("s_waitcnt lgkmcnt(0)" ::: "memory");  // own-wave P writes visible

      // O += P @ V
#pragma unroll
      for (int dt = 0; dt < 4; ++dt)
#pragma unroll
        for (int kt = 0; kt < 4; ++kt) {
          bfrag pf = *(const bfrag*)(&Ps[wid][lr * 128 + ((kt * 32 + lg * 8) ^ (sk << 3))]);
          int d = dt * 16 + lr;
          int fv = (d & 7) ^ ((d >> 3) & 7);
          bfrag vfb = *(const bfrag*)(Vt + d * 128 + ((kt * 32 + lg * 8) ^ (fv << 3)));
          o[rt][dt] = mfma16(pf, vfb, o[rt][dt]);
        }
    }
    __syncthreads();
  }

  // epilogue: normalize and store merged heads
#pragma unroll
  for (int rt = 0; rt < 2; ++rt) {
    f32x4 inv;
#pragma unroll
    for (int r = 0; r < 4; ++r) inv[r] = 1.f / l_[rt][r];
#pragma unroll
    for (int dt = 0; dt < 4; ++dt)
#pragma unroll
      for (int r = 0; r < 4; ++r)
        ao[(size_t)(b * 2048 + q0 + rt * 16 + lg * 4 + r) * 1024 + h * 64 + dt * 16 + lr] =
            f2bf(o[rt][dt][r] * inv[r]);
  }
}

extern "C" void kernel_launch(void* const* d_in, const int* in_sizes, int n_in,
                              void* d_out, int out_size, void* d_ws, size_t ws_size,
                              hipStream_t stream) {
  const float* y   = (const float*)d_in[0];
  const float* vf  = (const float*)d_in[1];
  const float* g   = (const float*)d_in[2];
  const float* bb  = (const float*)d_in[3];
  const float* Wq  = (const float*)d_in[4];
  const float* Wkv = (const float*)d_in[5];
  const float* Wo  = (const float*)d_in[6];
  float* out = (float*)d_out;
  char* ws = (char*)d_ws;

  u16* qb   = (u16*)(ws + 0ull);          // 8192x1024  (16 MB)
  u16* kvb  = (u16*)(ws + 16777216ull);   // 2048x2048  ( 8 MB)
  u16* aob  = (u16*)(ws + 25165824ull);   // 8192x1024  (16 MB)
  u16* wqT  = (u16*)(ws + 41943040ull);   // 1024x2048  ( 4 MB)
  u16* wkvT = (u16*)(ws + 46137344ull);   // 2048x1024  ( 4 MB)
  u16* woT  = (u16*)(ws + 50331648ull);   // 2048x1024  ( 4 MB)
  u16* vfb  = (u16*)(ws + 54525952ull);   // 2048x1024  ( 4 MB)
  // yn (8192x2048 bf16 = 32 MB) lives in d_out; consumed by Q-GEMM, then d_out
  // is fully overwritten by the final GEMM. Deterministic across replays.
  u16* yn = (u16*)d_out;

  dim3 tb(32, 8, 1);
  k_transpose<<<dim3(1024 / 32, 2048 / 32, 1), tb, 0, stream>>>(Wq, wqT, 2048, 1024);
  k_transpose<<<dim3(2048 / 32, 1024 / 32, 1), tb, 0, stream>>>(Wkv, wkvT, 1024, 2048);
  k_transpose<<<dim3(2048 / 32, 1024 / 32, 1), tb, 0, stream>>>(Wo, woT, 1024, 2048);
  k_cast<<<(2048 * 1024 / 8 + 255) / 256, 256, 0, stream>>>(vf, vfb, 2048 * 1024 / 8);
  k_layernorm<<<8192, 256, 0, stream>>>(y, g, bb, yn);
  // q = LN(y) @ Wq * 1/sqrt(64)
  k_gemm_bt<false><<<dim3(1024 / 128, 8192 / 128, 1), 256, 0, stream>>>(yn, wqT, qb, 8192, 1024, 2048, 0.125f);
  // kv = vis @ Wkv
  k_gemm_bt<false><<<dim3(2048 / 128, 2048 / 128, 1), 256, 0, stream>>>(vfb, wkvT, kvb, 2048, 2048, 1024, 1.0f);
  k_attn<<<dim3(16, 64, 1), 256, 0, stream>>>(qb, kvb, aob);
  // out = ao @ Wo (f32 out)
  k_gemm_bt<true><<<dim3(2048 / 128, 8192 / 128, 1), 256, 0, stream>>>(aob, woT, out, 8192, 2048, 1024, 1.0f);
}